// Round 1
// baseline (170.452 us; speedup 1.0000x reference)
//
#include <hip/hip_runtime.h>
#include <math.h>

// Fixed problem shape (ResonanceRotaryEmbedding): B=2, H=16, L=8192, DIM=128
#define BB   2
#define LL   8192
#define DIMM 128
#define D2   64
#define ROWS (BB * LL)     // 16384 rows of [DIM]
#define NPOS (BB * LL)     // 16384 position ids

#define NB 2048            // 8 blocks/CU -> 32 waves/CU -> 8 waves/SIMD
#define NT 256
#define RPB (ROWS / NB)    // 8 rows per block, 2 per wave

// ---------- pre-kernel: seq_len = max(position_ids) + 1 -> ws[0] ----------
__global__ void __launch_bounds__(1024)
seqlen_kernel(const int* __restrict__ pos, int* __restrict__ ws) {
    const int t = threadIdx.x;
    const int4* p4 = (const int4*)pos;          // 16384 ints = 4096 int4
    int m = -2147483647 - 1;
    #pragma unroll
    for (int i = 0; i < 4; ++i) {
        int4 v = p4[t + i * 1024];
        m = max(max(m, v.x), max(max(v.y, v.z), v.w));
    }
    #pragma unroll
    for (int off = 32; off > 0; off >>= 1)
        m = max(m, __shfl_down(m, off, 64));
    __shared__ int sm[16];
    if ((t & 63) == 0) sm[t >> 6] = m;
    __syncthreads();
    if (t == 0) {
        int r = sm[0];
        #pragma unroll
        for (int i = 1; i < 16; ++i) r = max(r, sm[i]);
        ws[0] = r + 1;
    }
}

// ---------- main kernel: one frequency d per lane, 2 rows per wave ----------
template <bool HAVE_WS>
__global__ void __launch_bounds__(NT)
rope_main(const int* __restrict__ pos,
          const float* __restrict__ inv_freq,
          const float* __restrict__ wavelengths,
          const int* __restrict__ seq_ptr,
          float* __restrict__ out) {
    const int t = threadIdx.x;

    int seq_len;
    if (HAVE_WS) {
        seq_len = *seq_ptr;                     // uniform scalar load
    } else {
        // fallback: per-block full reduction (correct, slower)
        int m = -2147483647 - 1;
        const int4* p4 = (const int4*)pos;
        for (int i = t; i < NPOS / 4; i += NT) {
            int4 v = p4[i];
            m = max(max(m, v.x), max(max(v.y, v.z), v.w));
        }
        #pragma unroll
        for (int off = 32; off > 0; off >>= 1)
            m = max(m, __shfl_down(m, off, 64));
        __shared__ int sm[NT / 64];
        __shared__ int s_seq;
        if ((t & 63) == 0) sm[t >> 6] = m;
        __syncthreads();
        if (t == 0) {
            int r = sm[0];
            #pragma unroll
            for (int i = 1; i < NT / 64; ++i) r = max(r, sm[i]);
            s_seq = r + 1;
        }
        __syncthreads();
        seq_len = s_seq;
    }

    // per-lane loop invariants: lane owns frequency d = lane (0..63)
    const int lane = t & 63;
    const int wv   = t >> 6;
    const int   w  = (int)wavelengths[lane];
    const float f  = inv_freq[lane];
    const bool  md = (w <= seq_len);
    const unsigned wu = (unsigned)w;

    float* __restrict__ cosb = out;
    float* __restrict__ sinb = out + (size_t)ROWS * DIMM;

    const int r0 = blockIdx.x * RPB + wv * (RPB / 4);   // 2 consecutive rows/wave
    #pragma unroll
    for (int k = 0; k < RPB / 4; ++k) {
        const int r = r0 + k;
        const int b = r >> 13;                  // r / LL
        const int l = r & (LL - 1);

        const unsigned i = md ? ((unsigned)l % wu) : (unsigned)l;
        const float p = (float)pos[(b << 13) + (int)i];
        const float a = p * f;                  // always < 2*pi
        const float c = __cosf(a);
        const float s = __sinf(a);

        // row layout: [cos(f0..f63), cos(f0..f63)] (concat duplication)
        const size_t base = (size_t)r * DIMM + lane;
        cosb[base]      = c;      // 64 lanes -> 256B contiguous store
        cosb[base + 64] = c;
        sinb[base]      = s;
        sinb[base + 64] = s;
    }
}

extern "C" void kernel_launch(void* const* d_in, const int* in_sizes, int n_in,
                              void* d_out, int out_size, void* d_ws, size_t ws_size,
                              hipStream_t stream) {
    // inputs: 0=x (unused, fp32), 1=position_ids (int32 [B,L]),
    //         2=r_inv_freq (fp32 [64]), 3=r_wavelengths (fp32 [64])
    const int*   pos  = (const int*)d_in[1];
    const float* finv = (const float*)d_in[2];
    const float* wav  = (const float*)d_in[3];
    float* out = (float*)d_out;

    if (d_ws != nullptr && ws_size >= sizeof(int)) {
        int* ws = (int*)d_ws;
        seqlen_kernel<<<1, 1024, 0, stream>>>(pos, ws);
        rope_main<true><<<NB, NT, 0, stream>>>(pos, finv, wav, ws, out);
    } else {
        rope_main<false><<<NB, NT, 0, stream>>>(pos, finv, wav, nullptr, out);
    }
}